// Round 6
// baseline (384.801 us; speedup 1.0000x reference)
//
#include <hip/hip_runtime.h>
#include <hip/hip_fp16.h>

#define DD 192
#define HH 192
#define WW 192
#define NVOX (DD * HH * WW)

// ---- fp16 tiled kernel: tile 16x16x8, halo 8 ----
#define TX 16
#define TY 16
#define TZ 8
#define RSX 32               // x: [-8,+24)
#define RSY 33               // y: [-8,+25)
#define RSZ 25               // z: [-8,+17)
#define ROWD 16              // dwords per x-row (32 halves)
#define SLABD (RSY * ROWD)   // 528 dwords per z-slab
#define RTOTH (RSZ * RSY * RSX)   // 26400 halves = 52.8 KB
#define NCH (RTOTH / 8)      // 3300 16-byte chunks
#define CH_SLAB (RSY * 4)    // 132 chunks per slab
#define NT 512
#define NBLK_H ((WW / TX) * (HH / TY) * (DD / TZ))   // 3456

#define AS1 __attribute__((address_space(1)))
#define AS3 __attribute__((address_space(3)))

// mov fp32 -> fp16 (contiguous, BW-bound)
__global__ __launch_bounds__(256) void conv_fp16(
    const float4* __restrict__ in, int4* __restrict__ out)
{
    const int i = blockIdx.x * 256 + threadIdx.x;   // 8 elements per thread
    const float4 a = in[2 * i];
    const float4 b = in[2 * i + 1];
    __half2 h0 = __floats2half2_rn(a.x, a.y);
    __half2 h1 = __floats2half2_rn(a.z, a.w);
    __half2 h2 = __floats2half2_rn(b.x, b.y);
    __half2 h3 = __floats2half2_rn(b.z, b.w);
    int4 o;
    o.x = *(int*)&h0; o.y = *(int*)&h1; o.z = *(int*)&h2; o.w = *(int*)&h3;
    out[i] = o;
}

__global__ __launch_bounds__(NT, 6) void warp_mse_h(
    const ushort* __restrict__ movh,
    const float* __restrict__ mov,
    const float* __restrict__ vf,
    const float* __restrict__ fix,
    const int* __restrict__ mask,
    float* __restrict__ acc,   // [0]=sum(sq*m), [1]=sum(m), [2]=done ctr
    float* __restrict__ out)
{
    __shared__ ushort smov[RTOTH + 8];   // +8 halves pad for branchless o+1 read
    __shared__ float s_sq[8], s_cnt[8];

    const int tid = threadIdx.x;
    const int bx0 = blockIdx.x * TX, by0 = blockIdx.y * TY, bz0 = blockIdx.z * TZ;
    const int x_lo = bx0 - 8, y_lo = by0 - 8, z_lo = bz0 - 8;

    // ---- prefetch compute inputs (consumed after staging barrier) ----
    const int lxg = (tid & 3) * 4;
    const int ly  = (tid >> 2) & 15;
    const int lz  = tid >> 6;            // 0..7
    const int gz = bz0 + lz, gy = by0 + ly, gx0 = bx0 + lxg;
    const int base = (gz * HH + gy) * WW + gx0;
    const float4 dz4 = *(const float4*)(vf + base);
    const float4 dy4 = *(const float4*)(vf + NVOX + base);
    const float4 dx4 = *(const float4*)(vf + 2 * NVOX + base);
    const float4 f4  = *(const float4*)(fix + base);
    const int4   m4  = *(const int4*)(mask + base);

    // ---- edge blocks: pre-zero LDS (masked DMA lanes keep zeros) ----
    const bool edge = (blockIdx.x == 0) | (blockIdx.x == 11) |
                      (blockIdx.y == 0) | (blockIdx.y == 11) |
                      (blockIdx.z == 0) | (blockIdx.z >= 22);
    if (edge) {
        int4* s4 = (int4*)smov;
        #pragma unroll
        for (int i = 0; i < 7; ++i) {
            const int q = tid + i * NT;
            if (q < NCH) s4[q] = make_int4(0, 0, 0, 0);
        }
        __syncthreads();
    }

    // ---- async stage fp16 region: global_load_lds width=16 (8 halves) ----
    #pragma unroll
    for (int i = 0; i < 7; ++i) {
        const int q = tid + i * NT;
        if (q < NCH) {
            const int rz = q / CH_SLAB;
            const int rem = q - rz * CH_SLAB;
            const int ry = rem >> 2;
            const int k  = rem & 3;
            const int gzs = z_lo + rz, gys = y_lo + ry, gxs = x_lo + 8 * k;
            const bool valid = ((unsigned)gzs < DD) & ((unsigned)gys < HH) &
                               ((unsigned)gxs < WW);   // x OOB is chunk-granular
            const int qb = i * NT + (tid & ~63);       // wave-uniform chunk base
            if (valid) {
                __builtin_amdgcn_global_load_lds(
                    (AS1 void*)(movh + ((gzs * HH + gys) * WW + gxs)),
                    (AS3 void*)(smov + 8 * qb), 16, 0, 0);
            }
        }
    }
    __syncthreads();

    // ---- compute ----
    const float dzv[4] = {dz4.x, dz4.y, dz4.z, dz4.w};
    const float dyv[4] = {dy4.x, dy4.y, dy4.z, dy4.w};
    const float dxv[4] = {dx4.x, dx4.y, dx4.z, dx4.w};
    const float fv[4]  = {f4.x, f4.y, f4.z, f4.w};
    const int   mv[4]  = {m4.x, m4.y, m4.z, m4.w};
    const uint* sdw = (const uint*)smov;

    float sq = 0.0f, cnt = 0.0f;

    #pragma unroll
    for (int j = 0; j < 4; ++j) {
        const float z = (float)gz + dzv[j];
        const float y = (float)gy + dyv[j];
        const float x = (float)(gx0 + j) + dxv[j];

        const float z0f = floorf(z), y0f = floorf(y), x0f = floorf(x);
        const float wz = z - z0f, wy = y - y0f, wx = x - x0f;
        const int z0 = (int)z0f, y0 = (int)y0f, x0 = (int)x0f;

        const int z0l = z0 - z_lo, y0l = y0 - y_lo, x0l = x0 - x_lo;
        const bool inbox = ((unsigned)z0l < RSZ - 1) & ((unsigned)y0l < RSY - 1) &
                           ((unsigned)x0l < RSX - 1);

        float v000, v001, v010, v011, v100, v101, v110, v111;
        if (inbox) {
            const int o = z0l * SLABD + y0l * ROWD + (x0l >> 1);
            const bool odd = (x0l & 1);
            const uint a00 = sdw[o],                const_cast_dummy0 = 0; (void)const_cast_dummy0;
            const uint b00 = sdw[o + 1];
            const uint a01 = sdw[o + ROWD];
            const uint b01 = sdw[o + ROWD + 1];
            const uint a10 = sdw[o + SLABD];
            const uint b10 = sdw[o + SLABD + 1];
            const uint a11 = sdw[o + SLABD + ROWD];
            const uint b11 = sdw[o + SLABD + ROWD + 1];
            auto pair = [&](uint A, uint B, float& l, float& r) {
                const float2 fa = __half22float2(*(const __half2*)&A);
                const float fb = __low2float(*(const __half2*)&B);
                l = odd ? fa.y : fa.x;
                r = odd ? fb   : fa.y;
            };
            pair(a00, b00, v000, v001);
            pair(a01, b01, v010, v011);
            pair(a10, b10, v100, v101);
            pair(a11, b11, v110, v111);
        } else {
            // rare: beyond halo — fp32 global fallback
            const int z1 = z0 + 1, y1 = y0 + 1, x1 = x0 + 1;
            const bool zi0 = (unsigned)z0 < DD, zi1 = (unsigned)z1 < DD;
            const bool yi0 = (unsigned)y0 < HH, yi1 = (unsigned)y1 < HH;
            const bool xi0 = (unsigned)x0 < WW, xi1 = (unsigned)x1 < WW;
            auto ld = [&](int iz, int iy, int ix, bool ok) -> float {
                return ok ? mov[(iz * HH + iy) * WW + ix] : 0.0f;
            };
            v000 = ld(z0, y0, x0, zi0 & yi0 & xi0);
            v001 = ld(z0, y0, x1, zi0 & yi0 & xi1);
            v010 = ld(z0, y1, x0, zi0 & yi1 & xi0);
            v011 = ld(z0, y1, x1, zi0 & yi1 & xi1);
            v100 = ld(z1, y0, x0, zi1 & yi0 & xi0);
            v101 = ld(z1, y0, x1, zi1 & yi0 & xi1);
            v110 = ld(z1, y1, x0, zi1 & yi1 & xi0);
            v111 = ld(z1, y1, x1, zi1 & yi1 & xi1);
        }

        const float c00 = v000 + (v001 - v000) * wx;
        const float c01 = v010 + (v011 - v010) * wx;
        const float c10 = v100 + (v101 - v100) * wx;
        const float c11 = v110 + (v111 - v110) * wx;
        const float c0 = c00 + (c01 - c00) * wy;
        const float c1 = c10 + (c11 - c10) * wy;
        const float warped = c0 + (c1 - c0) * wz;

        const float m = (mv[j] != 0) ? 1.0f : 0.0f;
        const float diff = warped - fv[j];
        sq += diff * diff * m;
        cnt += m;
    }

    // ---- reduction ----
    #pragma unroll
    for (int off = 32; off > 0; off >>= 1) {
        sq  += __shfl_down(sq, off, 64);
        cnt += __shfl_down(cnt, off, 64);
    }
    const int lane = tid & 63;
    const int wid = tid >> 6;   // 0..7
    if (lane == 0) { s_sq[wid] = sq; s_cnt[wid] = cnt; }
    __syncthreads();
    if (tid == 0) {
        float bsq = 0.0f, bcnt = 0.0f;
        #pragma unroll
        for (int i = 0; i < 8; ++i) { bsq += s_sq[i]; bcnt += s_cnt[i]; }
        atomicAdd(&acc[0], bsq);
        atomicAdd(&acc[1], bcnt);
        __threadfence();
        const unsigned old = atomicAdd((unsigned*)&acc[2], 1u);
        if (old == NBLK_H - 1) {
            __threadfence();
            const float s = atomicAdd(&acc[0], 0.0f);
            const float c = atomicAdd(&acc[1], 0.0f);
            out[0] = s / fmaxf(c, 1.0f);
        }
    }
}

// ---- fp32 single-buffer fallback (R5 kernel) if ws too small for movh ----
#define F32_RSX 32
#define F32_RSY 33
#define F32_RSZ 33
#define F32_SLAB (F32_RSY * F32_RSX)
#define F32_RTOT (F32_RSZ * F32_SLAB)
#define F32_NQ4 (F32_RTOT / 4)
#define F32_Q4SLAB (F32_SLAB / 4)
#define NBLK_F (12 * 12 * 12)

__global__ __launch_bounds__(1024) void warp_mse_f32(
    const float* __restrict__ mov, const float* __restrict__ vf,
    const float* __restrict__ fix, const int* __restrict__ mask,
    float* __restrict__ acc, float* __restrict__ out)
{
    __shared__ float smov[F32_RTOT];
    __shared__ float s_sq[16], s_cnt[16];
    const int tid = threadIdx.x;
    const int bx0 = blockIdx.x * 16, by0 = blockIdx.y * 16, bz0 = blockIdx.z * 16;
    const int x_lo = bx0 - 8, y_lo = by0 - 8, z_lo = bz0 - 8;
    const int lxg = (tid & 3) * 4, ly = (tid >> 2) & 15, lz = tid >> 6;
    const int gz = bz0 + lz, gy = by0 + ly, gx0 = bx0 + lxg;
    const int base = (gz * HH + gy) * WW + gx0;
    const float4 dz4 = *(const float4*)(vf + base);
    const float4 dy4 = *(const float4*)(vf + NVOX + base);
    const float4 dx4 = *(const float4*)(vf + 2 * NVOX + base);
    const float4 f4  = *(const float4*)(fix + base);
    const int4   m4  = *(const int4*)(mask + base);
    const bool edge = (blockIdx.x == 0) | (blockIdx.x == 11) |
                      (blockIdx.y == 0) | (blockIdx.y == 11) |
                      (blockIdx.z == 0) | (blockIdx.z == 11);
    if (edge) {
        float4* s4 = (float4*)smov;
        #pragma unroll
        for (int i = 0; i < 9; ++i) {
            const int q = tid + i * 1024;
            if (q < F32_NQ4) s4[q] = make_float4(0.f, 0.f, 0.f, 0.f);
        }
        __syncthreads();
    }
    #pragma unroll
    for (int i = 0; i < 9; ++i) {
        const int q = tid + i * 1024;
        if (q < F32_NQ4) {
            const int rz = q / F32_Q4SLAB;
            const int rem = q - rz * F32_Q4SLAB;
            const int ry = rem >> 3, k = rem & 7;
            const int gzs = z_lo + rz, gys = y_lo + ry, gxs = x_lo + 4 * k;
            const bool valid = ((unsigned)gzs < DD) & ((unsigned)gys < HH) &
                               ((unsigned)gxs < WW);
            const int qb = i * 1024 + (tid & ~63);
            if (valid)
                __builtin_amdgcn_global_load_lds(
                    (AS1 void*)(mov + ((gzs * HH + gys) * WW + gxs)),
                    (AS3 void*)(smov + 4 * qb), 16, 0, 0);
        }
    }
    __syncthreads();
    const float dzv[4] = {dz4.x, dz4.y, dz4.z, dz4.w};
    const float dyv[4] = {dy4.x, dy4.y, dy4.z, dy4.w};
    const float dxv[4] = {dx4.x, dx4.y, dx4.z, dx4.w};
    const float fv[4]  = {f4.x, f4.y, f4.z, f4.w};
    const int   mv[4]  = {m4.x, m4.y, m4.z, m4.w};
    float sq = 0.0f, cnt = 0.0f;
    #pragma unroll
    for (int j = 0; j < 4; ++j) {
        const float z = (float)gz + dzv[j];
        const float y = (float)gy + dyv[j];
        const float x = (float)(gx0 + j) + dxv[j];
        const float z0f = floorf(z), y0f = floorf(y), x0f = floorf(x);
        const float wz = z - z0f, wy = y - y0f, wx = x - x0f;
        const int z0 = (int)z0f, y0 = (int)y0f, x0 = (int)x0f;
        const int z0l = z0 - z_lo, y0l = y0 - y_lo, x0l = x0 - x_lo;
        const bool inbox = ((unsigned)z0l < F32_RSZ - 1) & ((unsigned)y0l < F32_RSY - 1) &
                           ((unsigned)x0l < F32_RSX - 1);
        float v000, v001, v010, v011, v100, v101, v110, v111;
        if (inbox) {
            const int o = z0l * F32_SLAB + y0l * F32_RSX + x0l;
            v000 = smov[o];           v001 = smov[o + 1];
            v010 = smov[o + F32_RSX]; v011 = smov[o + F32_RSX + 1];
            v100 = smov[o + F32_SLAB];           v101 = smov[o + F32_SLAB + 1];
            v110 = smov[o + F32_SLAB + F32_RSX]; v111 = smov[o + F32_SLAB + F32_RSX + 1];
        } else {
            const int z1 = z0 + 1, y1 = y0 + 1, x1 = x0 + 1;
            const bool zi0 = (unsigned)z0 < DD, zi1 = (unsigned)z1 < DD;
            const bool yi0 = (unsigned)y0 < HH, yi1 = (unsigned)y1 < HH;
            const bool xi0 = (unsigned)x0 < WW, xi1 = (unsigned)x1 < WW;
            auto ld = [&](int iz, int iy, int ix, bool ok) -> float {
                return ok ? mov[(iz * HH + iy) * WW + ix] : 0.0f;
            };
            v000 = ld(z0, y0, x0, zi0 & yi0 & xi0);
            v001 = ld(z0, y0, x1, zi0 & yi0 & xi1);
            v010 = ld(z0, y1, x0, zi0 & yi1 & xi0);
            v011 = ld(z0, y1, x1, zi0 & yi1 & xi1);
            v100 = ld(z1, y0, x0, zi1 & yi0 & xi0);
            v101 = ld(z1, y0, x1, zi1 & yi0 & xi1);
            v110 = ld(z1, y1, x0, zi1 & yi1 & xi0);
            v111 = ld(z1, y1, x1, zi1 & yi1 & xi1);
        }
        const float c00 = v000 + (v001 - v000) * wx;
        const float c01 = v010 + (v011 - v010) * wx;
        const float c10 = v100 + (v101 - v100) * wx;
        const float c11 = v110 + (v111 - v110) * wx;
        const float c0 = c00 + (c01 - c00) * wy;
        const float c1 = c10 + (c11 - c10) * wy;
        const float warped = c0 + (c1 - c0) * wz;
        const float m = (mv[j] != 0) ? 1.0f : 0.0f;
        const float diff = warped - fv[j];
        sq += diff * diff * m;
        cnt += m;
    }
    #pragma unroll
    for (int off = 32; off > 0; off >>= 1) {
        sq  += __shfl_down(sq, off, 64);
        cnt += __shfl_down(cnt, off, 64);
    }
    const int lane = tid & 63, wid = tid >> 6;
    if (lane == 0) { s_sq[wid] = sq; s_cnt[wid] = cnt; }
    __syncthreads();
    if (tid == 0) {
        float bsq = 0.0f, bcnt = 0.0f;
        #pragma unroll
        for (int i = 0; i < 16; ++i) { bsq += s_sq[i]; bcnt += s_cnt[i]; }
        atomicAdd(&acc[0], bsq);
        atomicAdd(&acc[1], bcnt);
        __threadfence();
        const unsigned old = atomicAdd((unsigned*)&acc[2], 1u);
        if (old == NBLK_F - 1) {
            __threadfence();
            const float s = atomicAdd(&acc[0], 0.0f);
            const float c = atomicAdd(&acc[1], 0.0f);
            out[0] = s / fmaxf(c, 1.0f);
        }
    }
}

extern "C" void kernel_launch(void* const* d_in, const int* in_sizes, int n_in,
                              void* d_out, int out_size, void* d_ws, size_t ws_size,
                              hipStream_t stream) {
    const float* mov  = (const float*)d_in[0];
    const float* vf   = (const float*)d_in[1];
    const float* fix  = (const float*)d_in[2];
    const int*   mask = (const int*)d_in[3];
    float* acc = (float*)d_ws;
    float* out = (float*)d_out;

    hipMemsetAsync(d_ws, 0, 4 * sizeof(float), stream);

    const size_t need = 256 + (size_t)NVOX * 2;
    if (ws_size >= need) {
        ushort* movh = (ushort*)((char*)d_ws + 256);
        conv_fp16<<<NVOX / (256 * 8), 256, 0, stream>>>(
            (const float4*)mov, (int4*)movh);
        dim3 grid(WW / TX, HH / TY, DD / TZ);   // 12 x 12 x 24
        warp_mse_h<<<grid, NT, 0, stream>>>(movh, mov, vf, fix, mask, acc, out);
    } else {
        dim3 grid(12, 12, 12);
        warp_mse_f32<<<grid, 1024, 0, stream>>>(mov, vf, fix, mask, acc, out);
    }
}

// Round 7
// 293.129 us; speedup vs baseline: 1.3127x; 1.3127x over previous
//
#include <hip/hip_runtime.h>
#include <hip/hip_fp16.h>

#define DD 192
#define HH 192
#define WW 192
#define NVOX (DD * HH * WW)

// tile 16x16x8, halo 8; staged region per tile: x32 [-8,+24) y33 [-8,+25) z25 [-8,+17)
#define TX 16
#define TY 16
#define TZ 8
#define RSX 32
#define RSY 33
#define RSZ 25
#define ROWD 16                    // dwords per x-row (32 halves)
#define SLABD (RSY * ROWD)         // 528 dwords per z-slab
#define RTOTH (RSZ * RSY * RSX)    // 26400 halves = 52800 B per buffer
#define NCHUNK (RTOTH / 8)         // 3300 16-byte DMA chunks
#define CH_SLAB (RSY * 4)          // 132 chunks per slab
#define NT 1024
#define NBLK (12 * 12 * 12)        // blocks; each does 2 z-adjacent tiles

#define AS1 __attribute__((address_space(1)))
#define AS3 __attribute__((address_space(3)))

// ---- mov fp32 -> fp16 (contiguous, BW-bound) ----
__global__ __launch_bounds__(256) void conv_fp16(
    const float4* __restrict__ in, int4* __restrict__ out)
{
    const int i = blockIdx.x * 256 + threadIdx.x;   // 8 elements per thread
    const float4 a = in[2 * i];
    const float4 b = in[2 * i + 1];
    __half2 h0 = __floats2half2_rn(a.x, a.y);
    __half2 h1 = __floats2half2_rn(a.z, a.w);
    __half2 h2 = __floats2half2_rn(b.x, b.y);
    __half2 h3 = __floats2half2_rn(b.z, b.w);
    int4 o;
    o.x = *(int*)&h0; o.y = *(int*)&h1; o.z = *(int*)&h2; o.w = *(int*)&h3;
    out[i] = o;
}

// ---- issue async DMA of one tile's fp16 region into an LDS buffer ----
// OOB chunks read from a zeroed 16B global region instead (zero-padding).
__device__ __forceinline__ void stage_tile(
    const ushort* __restrict__ movh, const ushort* __restrict__ zbuf,
    ushort* sbuf, int x_lo, int y_lo, int z_lo, int tid)
{
    #pragma unroll
    for (int i = 0; i < 4; ++i) {
        const int q = tid + i * NT;
        if (q < NCHUNK) {
            const int rz = q / CH_SLAB;
            const int rem = q - rz * CH_SLAB;
            const int ry = rem >> 2;
            const int k  = rem & 3;
            const int gz = z_lo + rz, gy = y_lo + ry, gx = x_lo + 8 * k;
            const bool valid = ((unsigned)gz < DD) & ((unsigned)gy < HH) &
                               ((unsigned)gx < WW);
            const ushort* src = valid ? (movh + ((gz * HH + gy) * WW + gx)) : zbuf;
            const int qb = i * NT + (tid & ~63);        // wave-uniform chunk base
            __builtin_amdgcn_global_load_lds((AS1 void*)src,
                                             (AS3 void*)(sbuf + 8 * qb), 16, 0, 0);
        }
    }
}

// ---- trilinear sample one voxel from an LDS fp16 buffer, accumulate loss ----
__device__ __forceinline__ void sample_accum(
    const uint* sdw, const float* __restrict__ mov,
    int gz, int gy, int gx, float dz, float dy, float dx,
    float f, int m, int x_lo, int y_lo, int z_lo,
    float& sq, float& cnt)
{
    const float z = (float)gz + dz, y = (float)gy + dy, x = (float)gx + dx;
    const float z0f = floorf(z), y0f = floorf(y), x0f = floorf(x);
    const float wz = z - z0f, wy = y - y0f, wx = x - x0f;
    const int z0 = (int)z0f, y0 = (int)y0f, x0 = (int)x0f;
    const int z0l = z0 - z_lo, y0l = y0 - y_lo, x0l = x0 - x_lo;
    const bool inbox = ((unsigned)z0l < RSZ - 1) & ((unsigned)y0l < RSY - 1) &
                       ((unsigned)x0l < RSX - 1);

    float v000, v001, v010, v011, v100, v101, v110, v111;
    if (inbox) {
        const int o = z0l * SLABD + y0l * ROWD + (x0l >> 1);
        const bool odd = (x0l & 1) != 0;
        const uint a00 = sdw[o];
        const uint b00 = sdw[o + 1];
        const uint a01 = sdw[o + ROWD];
        const uint b01 = sdw[o + ROWD + 1];
        const uint a10 = sdw[o + SLABD];
        const uint b10 = sdw[o + SLABD + 1];
        const uint a11 = sdw[o + SLABD + ROWD];
        const uint b11 = sdw[o + SLABD + ROWD + 1];
        auto pr = [&](uint A, uint B, float& l, float& r) {
            const float2 fa = __half22float2(*(const __half2*)&A);
            const float fb = __low2float(*(const __half2*)&B);
            l = odd ? fa.y : fa.x;
            r = odd ? fb   : fa.y;
        };
        pr(a00, b00, v000, v001);
        pr(a01, b01, v010, v011);
        pr(a10, b10, v100, v101);
        pr(a11, b11, v110, v111);
    } else {
        // rare (~0.2%/voxel): beyond halo — fp32 global fallback
        const int z1 = z0 + 1, y1 = y0 + 1, x1 = x0 + 1;
        const bool zi0 = (unsigned)z0 < DD, zi1 = (unsigned)z1 < DD;
        const bool yi0 = (unsigned)y0 < HH, yi1 = (unsigned)y1 < HH;
        const bool xi0 = (unsigned)x0 < WW, xi1 = (unsigned)x1 < WW;
        auto ld = [&](int iz, int iy, int ix, bool ok) -> float {
            return ok ? mov[(iz * HH + iy) * WW + ix] : 0.0f;
        };
        v000 = ld(z0, y0, x0, zi0 & yi0 & xi0);
        v001 = ld(z0, y0, x1, zi0 & yi0 & xi1);
        v010 = ld(z0, y1, x0, zi0 & yi1 & xi0);
        v011 = ld(z0, y1, x1, zi0 & yi1 & xi1);
        v100 = ld(z1, y0, x0, zi1 & yi0 & xi0);
        v101 = ld(z1, y0, x1, zi1 & yi0 & xi1);
        v110 = ld(z1, y1, x0, zi1 & yi1 & xi0);
        v111 = ld(z1, y1, x1, zi1 & yi1 & xi1);
    }

    const float c00 = v000 + (v001 - v000) * wx;
    const float c01 = v010 + (v011 - v010) * wx;
    const float c10 = v100 + (v101 - v100) * wx;
    const float c11 = v110 + (v111 - v110) * wx;
    const float c0 = c00 + (c01 - c00) * wy;
    const float c1 = c10 + (c11 - c10) * wy;
    const float warped = c0 + (c1 - c0) * wz;

    const float mm = (m != 0) ? 1.0f : 0.0f;
    const float diff = warped - f;
    sq += diff * diff * mm;
    cnt += mm;
}

// ---- pipelined 2-tile kernel: DMA(B) overlaps compute(A) ----
__global__ __launch_bounds__(NT) void warp_mse_pipe(
    const ushort* __restrict__ movh,
    const float* __restrict__ mov,
    const float* __restrict__ vf,
    const float* __restrict__ fix,
    const int* __restrict__ mask,
    const ushort* __restrict__ zbuf,
    float* __restrict__ acc,   // [0]=sum(sq*m), [1]=sum(m), [2]=done ctr
    float* __restrict__ out)
{
    __shared__ ushort sbuf[2][RTOTH];   // 2 x 52.8 KB
    __shared__ float s_sq[16], s_cnt[16];

    const int tid = threadIdx.x;
    const int bx0 = blockIdx.x * TX, by0 = blockIdx.y * TY;
    const int bzA = blockIdx.z * (2 * TZ);        // tile A: z [bzA, bzA+8)
    const int x_lo = bx0 - 8, y_lo = by0 - 8;
    const int z_loA = bzA - 8, z_loB = bzA;       // tile B: z [bzA+8, bzA+16)

    // thread -> 2 voxels (x, x+1)
    const int lx = (tid & 7) * 2;
    const int ly = (tid >> 3) & 15;
    const int lz = tid >> 7;                      // 0..7
    const int gy = by0 + ly, gx0 = bx0 + lx;
    const int gzA = bzA + lz, gzB = bzA + TZ + lz;

    // ---- issue DMA(A) + prologue(A) ----
    stage_tile(movh, zbuf, sbuf[0], x_lo, y_lo, z_loA, tid);
    const int baseA = (gzA * HH + gy) * WW + gx0;
    const float2 dzA = *(const float2*)(vf + baseA);
    const float2 dyA = *(const float2*)(vf + NVOX + baseA);
    const float2 dxA = *(const float2*)(vf + 2 * NVOX + baseA);
    const float2 fA  = *(const float2*)(fix + baseA);
    const int2   mA  = *(const int2*)(mask + baseA);

    __syncthreads();   // A staged (drains A's DMA)

    // ---- issue DMA(B) + prologue(B) — overlaps compute(A) ----
    stage_tile(movh, zbuf, sbuf[1], x_lo, y_lo, z_loB, tid);
    const int baseB = (gzB * HH + gy) * WW + gx0;
    const float2 dzB = *(const float2*)(vf + baseB);
    const float2 dyB = *(const float2*)(vf + NVOX + baseB);
    const float2 dxB = *(const float2*)(vf + 2 * NVOX + baseB);
    const float2 fB  = *(const float2*)(fix + baseB);
    const int2   mB  = *(const int2*)(mask + baseB);

    float sq = 0.0f, cnt = 0.0f;

    // ---- compute(A) ----
    const uint* sdw0 = (const uint*)sbuf[0];
    sample_accum(sdw0, mov, gzA, gy, gx0,     dzA.x, dyA.x, dxA.x, fA.x, mA.x,
                 x_lo, y_lo, z_loA, sq, cnt);
    sample_accum(sdw0, mov, gzA, gy, gx0 + 1, dzA.y, dyA.y, dxA.y, fA.y, mA.y,
                 x_lo, y_lo, z_loA, sq, cnt);

    __syncthreads();   // B staged

    // ---- compute(B) ----
    const uint* sdw1 = (const uint*)sbuf[1];
    sample_accum(sdw1, mov, gzB, gy, gx0,     dzB.x, dyB.x, dxB.x, fB.x, mB.x,
                 x_lo, y_lo, z_loB, sq, cnt);
    sample_accum(sdw1, mov, gzB, gy, gx0 + 1, dzB.y, dyB.y, dxB.y, fB.y, mB.y,
                 x_lo, y_lo, z_loB, sq, cnt);

    // ---- reduction: wave64 shuffle -> LDS -> one atomic pair per block ----
    #pragma unroll
    for (int off = 32; off > 0; off >>= 1) {
        sq  += __shfl_down(sq, off, 64);
        cnt += __shfl_down(cnt, off, 64);
    }
    const int lane = tid & 63;
    const int wid = tid >> 6;   // 0..15
    if (lane == 0) { s_sq[wid] = sq; s_cnt[wid] = cnt; }
    __syncthreads();
    if (tid == 0) {
        float bsq = 0.0f, bcnt = 0.0f;
        #pragma unroll
        for (int i = 0; i < 16; ++i) { bsq += s_sq[i]; bcnt += s_cnt[i]; }
        atomicAdd(&acc[0], bsq);
        atomicAdd(&acc[1], bcnt);
        __threadfence();
        const unsigned old = atomicAdd((unsigned*)&acc[2], 1u);
        if (old == NBLK - 1) {
            __threadfence();
            const float s = atomicAdd(&acc[0], 0.0f);
            const float c = atomicAdd(&acc[1], 0.0f);
            out[0] = s / fmaxf(c, 1.0f);
        }
    }
}

// ---- emergency fallback (ws too small): simple per-voxel kernel ----
__global__ __launch_bounds__(256) void warp_mse_simple(
    const float* __restrict__ mov, const float* __restrict__ vf,
    const float* __restrict__ fix, const int* __restrict__ mask,
    float* __restrict__ acc)
{
    const int idx = blockIdx.x * 256 + threadIdx.x;
    float sq = 0.0f, cnt = 0.0f;
    if (idx < NVOX) {
        const int w = idx % WW;
        const int t = idx / WW;
        const int h = t % HH;
        const int d = t / HH;
        const float z = (float)d + vf[idx];
        const float y = (float)h + vf[NVOX + idx];
        const float x = (float)w + vf[2 * NVOX + idx];
        const float z0f = floorf(z), y0f = floorf(y), x0f = floorf(x);
        const float wz = z - z0f, wy = y - y0f, wx = x - x0f;
        const int z0 = (int)z0f, y0 = (int)y0f, x0 = (int)x0f;
        const int z1 = z0 + 1, y1 = y0 + 1, x1 = x0 + 1;
        const bool zi0 = (unsigned)z0 < DD, zi1 = (unsigned)z1 < DD;
        const bool yi0 = (unsigned)y0 < HH, yi1 = (unsigned)y1 < HH;
        const bool xi0 = (unsigned)x0 < WW, xi1 = (unsigned)x1 < WW;
        auto ld = [&](int iz, int iy, int ix, bool ok) -> float {
            return ok ? mov[(iz * HH + iy) * WW + ix] : 0.0f;
        };
        const float v000 = ld(z0, y0, x0, zi0 & yi0 & xi0);
        const float v001 = ld(z0, y0, x1, zi0 & yi0 & xi1);
        const float v010 = ld(z0, y1, x0, zi0 & yi1 & xi0);
        const float v011 = ld(z0, y1, x1, zi0 & yi1 & xi1);
        const float v100 = ld(z1, y0, x0, zi1 & yi0 & xi0);
        const float v101 = ld(z1, y0, x1, zi1 & yi0 & xi1);
        const float v110 = ld(z1, y1, x0, zi1 & yi1 & xi0);
        const float v111 = ld(z1, y1, x1, zi1 & yi1 & xi1);
        const float c00 = v000 + (v001 - v000) * wx;
        const float c01 = v010 + (v011 - v010) * wx;
        const float c10 = v100 + (v101 - v100) * wx;
        const float c11 = v110 + (v111 - v110) * wx;
        const float c0 = c00 + (c01 - c00) * wy;
        const float c1 = c10 + (c11 - c10) * wy;
        const float warped = c0 + (c1 - c0) * wz;
        const float m = (mask[idx] != 0) ? 1.0f : 0.0f;
        const float diff = warped - fix[idx];
        sq = diff * diff * m;
        cnt = m;
    }
    #pragma unroll
    for (int off = 32; off > 0; off >>= 1) {
        sq  += __shfl_down(sq, off, 64);
        cnt += __shfl_down(cnt, off, 64);
    }
    __shared__ float s_sq[4], s_cnt[4];
    const int lane = threadIdx.x & 63, wid = threadIdx.x >> 6;
    if (lane == 0) { s_sq[wid] = sq; s_cnt[wid] = cnt; }
    __syncthreads();
    if (threadIdx.x == 0) {
        atomicAdd(&acc[0], s_sq[0] + s_sq[1] + s_sq[2] + s_sq[3]);
        atomicAdd(&acc[1], s_cnt[0] + s_cnt[1] + s_cnt[2] + s_cnt[3]);
    }
}

__global__ void warp_mse_finalize(const float* __restrict__ acc, float* __restrict__ out) {
    out[0] = acc[0] / fmaxf(acc[1], 1.0f);
}

extern "C" void kernel_launch(void* const* d_in, const int* in_sizes, int n_in,
                              void* d_out, int out_size, void* d_ws, size_t ws_size,
                              hipStream_t stream) {
    const float* mov  = (const float*)d_in[0];
    const float* vf   = (const float*)d_in[1];
    const float* fix  = (const float*)d_in[2];
    const int*   mask = (const int*)d_in[3];
    float* acc = (float*)d_ws;
    float* out = (float*)d_out;

    // [0,16): acc; [64,80): zero DMA source; [256,...): movh
    hipMemsetAsync(d_ws, 0, 256, stream);

    const size_t need = 256 + (size_t)NVOX * 2;
    if (ws_size >= need) {
        ushort* movh = (ushort*)((char*)d_ws + 256);
        const ushort* zbuf = (const ushort*)((char*)d_ws + 64);
        conv_fp16<<<NVOX / (256 * 8), 256, 0, stream>>>(
            (const float4*)mov, (int4*)movh);
        dim3 grid(WW / TX, HH / TY, DD / (2 * TZ));   // 12 x 12 x 12
        warp_mse_pipe<<<grid, NT, 0, stream>>>(movh, mov, vf, fix, mask, zbuf,
                                               acc, out);
    } else {
        warp_mse_simple<<<(NVOX + 255) / 256, 256, 0, stream>>>(mov, vf, fix, mask, acc);
        warp_mse_finalize<<<1, 1, 0, stream>>>(acc, out);
    }
}